// Round 14
// baseline (479.361 us; speedup 1.0000x reference)
//
#include <hip/hip_runtime.h>

typedef unsigned short ushort_t;

#define NN 10000
#define BB 8
#define TT 12
#define FF 8
#define HH 64
#define GG 192   // 3H
#define HORZ 12
#define EE 320000
#define MM (BB*NN) // 80000

// exp2-folding constants (r17): R/Z pre-activations scaled by -log2e,
// N pre-activations scaled by 2*log2e, folded into weights/biases.
#define NL2E (-1.4426950408889634f)
#define P2L2E (2.8853900817779268f)

// ---- ws layout (float words) ----
#define OFF_H    0u
#define OFF_F1   5120000u
#define OFF_F2   10240000u
#define OFF_B1   15360000u
#define OFF_B2   20480000u
#define OFF_BIAS 25600000u
#define OFF_W1   27520000u
#define OFF_DEGF 27521536u
#define OFF_DEGB 27531536u
#define OFF_CNTF 27541536u
#define OFF_CNTB 27551536u
#define OFF_PTRF 27561536u
#define OFF_PTRB 27571537u
#define OFF_EPKF 27581538u   // packed (idx, w) int2 per edge, fwd (640000 words)
#define OFF_EPKB 28221538u   // packed (idx, w) int2 per edge, bwd (640000 words)
#define OFF_FLAG 28861538u
// r18: bf16 B-frag packs for MFMA filtdec (appended; +53KB of 115MB ws)
#define OFF_FWPK 28861540u   // filtW frags: 40 sets * 64 lanes * int4 = 10240 words
#define OFF_DWPK 28871780u   // decW frags: 12 sets * 64 lanes * int4 = 3072 words

typedef __attribute__((ext_vector_type(8))) short short8;
typedef __attribute__((ext_vector_type(4))) float f4v;

union I4S8 { int4 i; short8 s; };

__device__ __forceinline__ f4v mfma16(int4 a, int4 b, f4v c) {
    I4S8 ua, ub; ua.i = a; ub.i = b;
    return __builtin_amdgcn_mfma_f32_16x16x32_bf16(ua.s, ub.s, c, 0, 0, 0);
}

__device__ __forceinline__ unsigned f2bf_u(float f) {
    union { float f; unsigned u; } v; v.f = f;
    unsigned x = v.u;
    x += 0x7FFFu + ((x >> 16) & 1u);
    return x >> 16;
}
// pack 8 fp32 -> bf16 (round-to-nearest) fragment
__device__ __forceinline__ int4 hi8(const float* f) {
    unsigned hb[8];
    #pragma unroll
    for (int i = 0; i < 8; i++) hb[i] = f2bf_u(f[i]);
    return make_int4((int)(hb[0]|(hb[1]<<16)), (int)(hb[2]|(hb[3]<<16)),
                     (int)(hb[4]|(hb[5]<<16)), (int)(hb[6]|(hb[7]<<16)));
}
// hi/lo split pack: ahi = bf16(x), alo = bf16(x - float(ahi)) — near-fp32 A operand
__device__ __forceinline__ void hilo8(const float* f, int4* ahi, int4* alo) {
    unsigned hb[8];
    float fl[8];
    #pragma unroll
    for (int i = 0; i < 8; i++) {
        hb[i] = f2bf_u(f[i]);
        union { unsigned u; float f; } hf; hf.u = hb[i] << 16;
        fl[i] = f[i] - hf.f;
    }
    *ahi = make_int4((int)(hb[0]|(hb[1]<<16)), (int)(hb[2]|(hb[3]<<16)),
                     (int)(hb[4]|(hb[5]<<16)), (int)(hb[6]|(hb[7]<<16)));
    *alo = hi8(fl);
}

__device__ __forceinline__ float f4c(const float4& v, int kk) {
    switch (kk) { case 0: return v.x; case 1: return v.y; case 2: return v.z; default: return v.w; }
}
#define FMA4(ACC, W, S) \
    ACC[0] = fmaf(S, W.x, ACC[0]); \
    ACC[1] = fmaf(S, W.y, ACC[1]); \
    ACC[2] = fmaf(S, W.z, ACC[2]); \
    ACC[3] = fmaf(S, W.w, ACC[3]);

// ---------------- utility ----------------
__global__ void zero_k(float* p, int n) {
    int i = blockIdx.x * 256 + threadIdx.x;
    if (i < n) p[i] = 0.f;
}

__global__ void flag_k(const int* __restrict__ ei, int* flag) {
    if (threadIdx.x == 0 && blockIdx.x == 0) {
        int o = ei[1] | ei[3] | ei[5] | ei[7] | ei[9] | ei[11] | ei[13];
        flag[0] = (o == 0) ? 1 : 0;
    }
}

__device__ __forceinline__ void load_edge(const int* __restrict__ ei, int isI64,
                                          int e, int& s, int& t) {
    if (isI64) {
        const long long* p = (const long long*)ei;
        s = (int)p[e]; t = (int)p[EE + e];
    } else {
        s = ei[e]; t = ei[EE + e];
    }
}

// ---------------- CSR build ----------------
__global__ void csr_count_k(const int* __restrict__ ei, const float* __restrict__ ew,
                            const int* __restrict__ flag,
                            int* cnt_f, int* cnt_b, float* deg_f, float* deg_b) {
    int e = blockIdx.x * 256 + threadIdx.x;
    if (e >= EE) return;
    int isI64 = flag[0];
    int s, t; load_edge(ei, isI64, e, s, t);
    if ((unsigned)s >= NN || (unsigned)t >= NN) return;
    float w = ew[e];
    atomicAdd(&cnt_f[t], 1); atomicAdd(&deg_f[t], w);
    atomicAdd(&cnt_b[s], 1); atomicAdd(&deg_b[s], w);
}

__global__ void scan_k(int* cnt_f, int* cnt_b, int* ptr_f, int* ptr_b) {
    int* cnt = blockIdx.x ? cnt_b : cnt_f;
    int* ptr = blockIdx.x ? ptr_b : ptr_f;
    __shared__ int part[256];
    int tid = threadIdx.x;
    const int CH = (NN + 255) / 256;
    int lo = tid * CH, hi = lo + CH; if (hi > NN) hi = NN; if (lo > NN) lo = NN;
    int s = 0;
    for (int i = lo; i < hi; i++) s += cnt[i];
    part[tid] = s;
    __syncthreads();
    if (tid == 0) {
        int run = 0;
        for (int i = 0; i < 256; i++) { int v = part[i]; part[i] = run; run += v; }
        ptr[NN] = run;
    }
    __syncthreads();
    int run = part[tid];
    for (int i = lo; i < hi; i++) { ptr[i] = run; run += cnt[i]; cnt[i] = 0; }
}

__global__ void csr_fill_k(const int* __restrict__ ei, const float* __restrict__ ew,
                           const int* __restrict__ flag,
                           const float* __restrict__ deg_f, const float* __restrict__ deg_b,
                           const int* __restrict__ ptr_f, const int* __restrict__ ptr_b,
                           int* cnt_f, int* cnt_b,
                           int* epk_f, int* epk_b) {
    int e = blockIdx.x * 256 + threadIdx.x;
    if (e >= EE) return;
    int isI64 = flag[0];
    int s, t; load_edge(ei, isI64, e, s, t);
    if ((unsigned)s >= NN || (unsigned)t >= NN) return;
    float w = ew[e];
    float df = deg_f[t];
    float nwf = w / ((df == 0.f) ? 1.f : df);
    int p = ptr_f[t] + atomicAdd(&cnt_f[t], 1);
    epk_f[2 * p] = s; epk_f[2 * p + 1] = __float_as_int(nwf);
    float db = deg_b[s];
    float nwb = w / ((db == 0.f) ? 1.f : db);
    int p2 = ptr_b[s] + atomicAdd(&cnt_b[s], 1);
    epk_b[2 * p2] = t; epk_b[2 * p2 + 1] = __float_as_int(nwb);
}

// ---------------- precompute W1 = enc_W @ Wih^T  [8][192] ----------------
// r17: exp2-folding — R/Z columns (g<128) scaled by -log2e, N columns by
// 2*log2e, so gru_k gates use raw v_exp_f32 (exp2) with no scale VALU.
__global__ void w1_k(const float* __restrict__ encW, const float* __restrict__ wih,
                     float* __restrict__ W1) {
    int id = blockIdx.x * 256 + threadIdx.x;
    if (id >= FF * GG) return;
    int f = id / GG, g = id - f * GG;
    float acc = 0.f;
    for (int hh = 0; hh < HH; hh++)
        acc = fmaf(encW[f * HH + hh], wih[g * HH + hh], acc);
    W1[id] = acc * ((g < 128) ? NL2E : P2L2E);
}

// ---------------- r18: pack filtW/decW into bf16 B-frags (frag-linear) ----------
__global__ void pack_k(const float* __restrict__ filtW, const float* __restrict__ decW,
                       int* __restrict__ fwpk, int* __restrict__ dwpk) {
    int id = blockIdx.x * 256 + threadIdx.x;
    int ln = id & 63, set = id >> 6;
    int quad = ln >> 4, lx = ln & 15;
    if (set < 40) {
        int ks = set >> 2, ct = set & 3;
        float fv[8];
        #pragma unroll
        for (int j = 0; j < 8; j++)
            fv[j] = filtW[(ks * 32 + quad * 8 + j) * 64 + ct * 16 + lx];
        *(int4*)&fwpk[(set * 64 + ln) * 4] = hi8(fv);
    } else if (set < 52) {
        int s2 = set - 40;
        int ks2 = s2 / 6, ct2 = s2 - ks2 * 6;
        float fv[8];
        #pragma unroll
        for (int j = 0; j < 8; j++)
            fv[j] = decW[(ks2 * 32 + quad * 8 + j) * 96 + ct2 * 16 + lx];
        *(int4*)&dwpk[(s2 * 64 + ln) * 4] = hi8(fv);
    }
}

// ---- biasA[n][g] = bih[g] + (g<128? bhh[g]:0) + sum_h (enc_b+emb[n])*Wih[g][h] ----
__global__ __launch_bounds__(256, 2)
void biasA_k(const float* __restrict__ emb, const float* __restrict__ encb,
             const float* __restrict__ wih, const float* __restrict__ bih,
             const float* __restrict__ bhh, float* __restrict__ biasA) {
    __shared__ float wl[HH * GG];   // wl[h][g] = Wih[g][h]
    __shared__ float et[64 * 68];   // enc_b + emb tile
    const int tid = threadIdx.x;
    const int n0 = blockIdx.x * 64;
    for (int idx = tid * 4; idx < GG * HH; idx += 1024) {
        float4 v = *(const float4*)&wih[idx];
        int g = idx >> 6, hh = idx & 63;
        wl[hh * GG + g] = v.x;
        wl[(hh + 1) * GG + g] = v.y;
        wl[(hh + 2) * GG + g] = v.z;
        wl[(hh + 3) * GG + g] = v.w;
    }
    {
        int row = tid >> 2, cc = (tid & 3) * 16;
        int n = n0 + row;
        #pragma unroll
        for (int u = 0; u < 4; u++) {
            float4 e4 = (n < NN) ? *(const float4*)&emb[(size_t)n * HH + cc + u * 4]
                                 : make_float4(0.f, 0.f, 0.f, 0.f);
            float4 b4 = *(const float4*)&encb[cc + u * 4];
            *(float4*)&et[row * 68 + cc + u * 4] =
                make_float4(e4.x + b4.x, e4.y + b4.y, e4.z + b4.z, e4.w + b4.w);
        }
    }
    __syncthreads();
    const int r0 = (tid >> 4) * 4;
    #pragma unroll 1
    for (int p = 0; p < 3; p++) {
        const int c0 = p * 64 + (tid & 15) * 4;
        float acc[4][4];
        float4 bi = *(const float4*)&bih[c0];
        float4 bh = (c0 < 128) ? *(const float4*)&bhh[c0] : make_float4(0.f, 0.f, 0.f, 0.f);
        #pragma unroll
        for (int i = 0; i < 4; i++) {
            acc[i][0] = bi.x + bh.x; acc[i][1] = bi.y + bh.y;
            acc[i][2] = bi.z + bh.z; acc[i][3] = bi.w + bh.w;
        }
        #pragma unroll 4
        for (int k4 = 0; k4 < 64; k4 += 4) {
            float4 hv[4];
            #pragma unroll
            for (int i = 0; i < 4; i++)
                hv[i] = *(const float4*)&et[(r0 + i) * 68 + k4];
            #pragma unroll
            for (int kk = 0; kk < 4; kk++) {
                const float4 wv = *(const float4*)&wl[(k4 + kk) * GG + c0];
                #pragma unroll
                for (int i = 0; i < 4; i++) {
                    float a_ = f4c(hv[i], kk);
                    FMA4(acc[i], wv, a_);
                }
            }
        }
        #pragma unroll
        for (int i = 0; i < 4; i++) {
            int n = n0 + r0 + i;
            if (n < NN)
                *(float4*)&biasA[(size_t)n * GG + c0] =
                    make_float4(acc[i][0], acc[i][1], acc[i][2], acc[i][3]);
        }
    }
}

// ---------------- MFMA GRU: all 12 steps, no barriers in loop ----------------
// h scratch bf16 in A-fragment layout; reads via __builtin_memcpy (alias-safe —
// ushort stores + typed 64b loads were reordered by TBAA in the r7 NaN bug).
// r8 WIN kept: gates div-free. r8 FAILED: launch_bounds(256,4) -> spills.
// r16 NEUTRAL kept: w1f in LDS. r17 WIN: exp2-folding.
// r19 FAILED reverted: per-j MFMA+gate fusion cut VGPR 116->96 but dur
//   78.5->88us — MfmaUtil AND VALUBusy both fell. The 4 separated j-streams
//   were buying ILP (gates(j) hid under MFMAs(j')); fusing serialized the
//   dependency chain. LESSON: peak-live reg reduction is worthless if it
//   serializes the dep graph. This is the r17 structure (known 78.5us).
__global__ __launch_bounds__(256, 2)
void gru_k(const float* __restrict__ x, const float* __restrict__ biasA,
           const float* __restrict__ W1, const float* __restrict__ whh,
           const float* __restrict__ bhh, float* __restrict__ h_out) {
    __shared__ int lds_B[24 * 64 * 4];                     // Whh B-frags (24 KB)
    __shared__ int lds_W1[12 * 64 * 4];                    // W1 B-frags (12 KB)
    __shared__ __align__(16) ushort_t lds_hb[4][16 * 68];  // per-wave h bf16

    const int tid = threadIdx.x;
    const int wave = tid >> 6, ln = tid & 63;
    const int quad = ln >> 4, lx = ln & 15;
    const int m0 = blockIdx.x * 64;
    ushort_t* hbw = (ushort_t*)lds_hb[wave];

    // stage Whh B-frags: fid=(c*2+q): B[k = q*32 + (ln>>4)*8 + j][g = c*16 + (ln&15)]
    // r17: columns c<8 (R,Z) scaled by -log2e; c>=8 (N) by 2*log2e.
    #pragma unroll
    for (int it = 0; it < 6; it++) {
        int slot = tid + it * 256;
        int fid = slot >> 6, l2 = slot & 63;
        int c = fid >> 1, q = fid & 1;
        int g = c * 16 + (l2 & 15);
        int k0 = q * 32 + ((l2 >> 4) & 3) * 8;
        float sc = (c < 8) ? NL2E : P2L2E;
        const float* wp = whh + (size_t)g * HH + k0;
        float4 v0 = *(const float4*)wp;
        float4 v1 = *(const float4*)(wp + 4);
        float fv[8] = {v0.x * sc, v0.y * sc, v0.z * sc, v0.w * sc,
                       v1.x * sc, v1.y * sc, v1.z * sc, v1.w * sc};
        *(int4*)&lds_B[slot * 4] = hi8(fv);
    }

    // stage W1 B-frags to LDS (block-uniform; already exp2-scaled by w1_k;
    // K=32 padded, only k<8 real -> lanes 0-15 carry data)
    #pragma unroll
    for (int it = 0; it < 3; it++) {
        int slot = tid + it * 256;
        int f = slot >> 6, l2 = slot & 63;
        int4 v = make_int4(0, 0, 0, 0);
        if (l2 < 16) {
            int col = f * 16 + l2;
            float fv[8];
            #pragma unroll
            for (int k = 0; k < 8; k++) fv[k] = W1[k * GG + col];
            v = hi8(fv);
        }
        *(int4*)&lds_W1[slot * 4] = v;
    }

    // per-lane biases (C-layout positions), exp2-scaled at load
    f4v bR[4], bZ[4], bNx[4];
    float bHn[4];
    int rown[4];
    #pragma unroll
    for (int reg = 0; reg < 4; reg++) {
        int m = m0 + wave * 16 + quad * 4 + reg;
        int b = m / NN; rown[reg] = m - b * NN;
    }
    #pragma unroll
    for (int j = 0; j < 4; j++) {
        int c = j * 16 + lx;
        #pragma unroll
        for (int reg = 0; reg < 4; reg++) {
            const float* bp = biasA + (size_t)rown[reg] * GG;
            bR[j][reg]  = bp[c] * NL2E;
            bZ[j][reg]  = bp[64 + c] * NL2E;
            bNx[j][reg] = bp[128 + c] * P2L2E;
        }
        bHn[j] = bhh[128 + c] * P2L2E;
    }

    // x pointer + first-step preload (rows owned: m0 + wave*16 + ln, lanes 0-15)
    const float* xp = x;
    float4 xc0 = make_float4(0.f,0.f,0.f,0.f), xc1 = xc0;
    if (ln < 16) {
        int m = m0 + wave * 16 + ln;
        int b = m / NN; int n = m - b * NN;
        xp = x + ((size_t)(b * TT) * NN + n) * FF;
        xc0 = *(const float4*)xp;
        xc1 = *(const float4*)(xp + 4);
    }

    __syncthreads();   // lds_B + lds_W1 ready (only barrier)

    f4v hp[4];
    #pragma unroll
    for (int j = 0; j < 4; j++) hp[j] = (f4v){0.f, 0.f, 0.f, 0.f};

    #pragma unroll 1
    for (int t = 0; t < TT; t++) {
        // pack current x A-frag (hi only)
        int4 axh = make_int4(0, 0, 0, 0);
        {
            float fv[8] = {xc0.x, xc0.y, xc0.z, xc0.w, xc1.x, xc1.y, xc1.z, xc1.w};
            if (ln < 16) axh = hi8(fv);
        }
        // prefetch next-step x (in flight during MFMAs + gates)
        if (t < TT - 1 && ln < 16) {
            const float* xq = xp + (size_t)(t + 1) * (NN * FF);
            xc0 = *(const float4*)xq;
            xc1 = *(const float4*)(xq + 4);
        }

        // h A-frags from bf16 LDS (A-layout: row=lx, chans q*32+quad*8..+7)
        int4 ahf[2];
        if (t) {
            const ushort_t* h0 = hbw + lx * 68 + quad * 8;
            long long a00, a01, a10, a11;
            __builtin_memcpy(&a00, h0, 8);
            __builtin_memcpy(&a01, h0 + 4, 8);
            __builtin_memcpy(&a10, h0 + 32, 8);
            __builtin_memcpy(&a11, h0 + 36, 8);
            ahf[0] = make_int4((int)a00, (int)(a00 >> 32), (int)a01, (int)(a01 >> 32));
            ahf[1] = make_int4((int)a10, (int)(a10 >> 32), (int)a11, (int)(a11 >> 32));
        }

        f4v accR[4], accZ[4], accNx[4], accNh[4];
        #pragma unroll
        for (int j = 0; j < 4; j++) {
            int4 wR = *(const int4*)&lds_W1[((j    ) * 64 + ln) * 4];
            int4 wZ = *(const int4*)&lds_W1[((j + 4) * 64 + ln) * 4];
            int4 wN = *(const int4*)&lds_W1[((j + 8) * 64 + ln) * 4];
            accR[j]  = mfma16(axh, wR, bR[j]);
            accZ[j]  = mfma16(axh, wZ, bZ[j]);
            accNx[j] = mfma16(axh, wN, bNx[j]);
            accNh[j] = (f4v){bHn[j], bHn[j], bHn[j], bHn[j]};
        }
        if (t) {
            #pragma unroll
            for (int j = 0; j < 4; j++) {
                #pragma unroll
                for (int q = 0; q < 2; q++) {
                    int4 bRf = *(const int4*)&lds_B[((j * 2 + q) * 64 + ln) * 4];
                    int4 bZf = *(const int4*)&lds_B[(((j + 4) * 2 + q) * 64 + ln) * 4];
                    int4 bNf = *(const int4*)&lds_B[(((j + 8) * 2 + q) * 64 + ln) * 4];
                    accR[j]  = mfma16(ahf[q], bRf, accR[j]);
                    accZ[j]  = mfma16(ahf[q], bZf, accZ[j]);
                    accNh[j] = mfma16(ahf[q], bNf, accNh[j]);
                }
            }
        }

        // gates (exp2-folded): rr = rcp(1+exp2(accR')), nn = 1-2*rcp(exp2(pre')+1)
        #pragma unroll
        for (int j = 0; j < 4; j++) {
            #pragma unroll
            for (int reg = 0; reg < 4; reg++) {
                float rr = __builtin_amdgcn_rcpf(1.f + __builtin_amdgcn_exp2f(accR[j][reg]));
                float zz = __builtin_amdgcn_rcpf(1.f + __builtin_amdgcn_exp2f(accZ[j][reg]));
                float pre = fmaf(rr, accNh[j][reg], accNx[j][reg]);
                float e2 = __builtin_amdgcn_exp2f(pre);
                float nn = fmaf(-2.f, __builtin_amdgcn_rcpf(e2 + 1.f), 1.f);
                float hv = fmaf(zz, hp[j][reg] - nn, nn);
                hp[j][reg] = hv;
                hbw[(quad * 4 + reg) * 68 + j * 16 + lx] = (ushort_t)f2bf_u(hv);
            }
        }
    }

    // epilogue: h_out[m][64] straight from registers (C-layout, 64B segments)
    #pragma unroll
    for (int j = 0; j < 4; j++) {
        #pragma unroll
        for (int reg = 0; reg < 4; reg++) {
            int m = m0 + wave * 16 + quad * 4 + reg;
            h_out[(size_t)m * HH + j * 16 + lx] = hp[j][reg];
        }
    }
}

// ---------------- diffusion: uniform-node scalar-addressed gather ----------------
// r9 FAILED: 8 batches/wave killed L2 locality. r10 WIN: scalar addressing.
// r11 FAILED: tid>>6 not provably uniform. r12 WIN: readfirstlane + 1-slice.
// r13 WIN (small): unroll 16. r14 WIN: XCD-pinned batch.
// r20: MLP 16 -> 32 (latency-bound per r12/r13 evidence; mean degree 32 so
//   the 32-block covers ~half the edge mass). Arrays with full-unroll static
//   indexing (rule #20-safe). VGPR ~20 -> ~100, still >=4 waves/SIMD at
//   128-thr blocks. Tails: 16 / 8 / scalar.
__global__ __launch_bounds__(128)
void prop_k(const float* __restrict__ srcF, float* __restrict__ dstF,
            const int* __restrict__ ptrF, const long long* __restrict__ epkF,
            const float* __restrict__ srcB, float* __restrict__ dstB,
            const int* __restrict__ ptrB, const long long* __restrict__ epkB) {
    const int wv = __builtin_amdgcn_readfirstlane(threadIdx.x >> 6);  // SGPR
    const int ln = threadIdx.x & 63;
    const int b = blockIdx.x & 7;                // XCD-pinned batch
    const int node = (blockIdx.x >> 3) * 2 + wv; // provably wave-uniform
    const float* src; float* dst; const int* ptr; const long long* ep;
    if (blockIdx.z == 0) { src = srcF; dst = dstF; ptr = ptrF; ep = epkF; }
    else                 { src = srcB; dst = dstB; ptr = ptrB; ep = epkB; }
    const int uoff = b * (NN * HH) + ln;         // loop-invariant lane offset
    const int e0 = ptr[node], e1 = ptr[node + 1];

    float a[8];
    #pragma unroll
    for (int u = 0; u < 8; u++) a[u] = 0.f;
    int j = e0;
    for (; j + 32 <= e1; j += 32) {
        long long r[32];
        #pragma unroll
        for (int u = 0; u < 32; u++) r[u] = ep[j + u];
        float v[32];
        #pragma unroll
        for (int u = 0; u < 32; u++)
            v[u] = (src + ((size_t)(int)r[u] << 6))[uoff];
        #pragma unroll
        for (int u = 0; u < 32; u++)
            a[u & 7] = fmaf(v[u], __int_as_float((int)(r[u] >> 32)), a[u & 7]);
    }
    for (; j + 16 <= e1; j += 16) {
        long long r[16];
        #pragma unroll
        for (int u = 0; u < 16; u++) r[u] = ep[j + u];
        float v[16];
        #pragma unroll
        for (int u = 0; u < 16; u++)
            v[u] = (src + ((size_t)(int)r[u] << 6))[uoff];
        #pragma unroll
        for (int u = 0; u < 16; u++)
            a[u & 7] = fmaf(v[u], __int_as_float((int)(r[u] >> 32)), a[u & 7]);
    }
    for (; j + 8 <= e1; j += 8) {
        long long r[8];
        #pragma unroll
        for (int u = 0; u < 8; u++) r[u] = ep[j + u];
        float v[8];
        #pragma unroll
        for (int u = 0; u < 8; u++)
            v[u] = (src + ((size_t)(int)r[u] << 6))[uoff];
        #pragma unroll
        for (int u = 0; u < 8; u++)
            a[u] = fmaf(v[u], __int_as_float((int)(r[u] >> 32)), a[u]);
    }
    for (; j < e1; j++) {
        long long r0 = ep[j];
        a[0] = fmaf((src + ((size_t)(int)r0 << 6))[uoff],
                    __int_as_float((int)(r0 >> 32)), a[0]);
    }
    float s = ((a[0] + a[1]) + (a[2] + a[3])) + ((a[4] + a[5]) + (a[6] + a[7]));
    __builtin_nontemporal_store(s, &dst[((size_t)b * NN + node) * HH + ln]);
}

// ---------------- r18: MFMA filter (K=320) + decoder (K=64) ----------------
// r18 WIN: matrix-core rewrite (prepacked bf16 B-frags, hi/lo-split A, zero
// barriers, LDS 8.7KB): filtdec out of top-5, absmax unchanged.
__global__ __launch_bounds__(256)
void filtdec_k(const float* __restrict__ h, const float* __restrict__ f1,
               const float* __restrict__ f2, const float* __restrict__ b1,
               const float* __restrict__ b2,
               const int4* __restrict__ fwpk, const float* __restrict__ filtb,
               const int4* __restrict__ dwpk, const float* __restrict__ decb,
               float* __restrict__ out) {
    __shared__ __align__(16) ushort_t lds_z[4][16 * 68];
    const int tid = threadIdx.x;
    const int wave = tid >> 6, ln = tid & 63;
    const int quad = ln >> 4, lx = ln & 15;
    const int m0 = blockIdx.x * 64;
    const int arow = m0 + wave * 16 + lx;        // A-frag row for this lane
    ushort_t* zb = (ushort_t*)lds_z[wave];

    // filter accumulators, bias-initialized (C-layout: col = ct*16+lx)
    f4v zacc[4];
    #pragma unroll
    for (int ct = 0; ct < 4; ct++) {
        float fb = filtb[ct * 16 + lx];
        zacc[ct] = (f4v){fb, fb, fb, fb};
    }

    // K = 320 = 5 matrices x 64; per matrix 2 K-steps of 32
    #pragma unroll 1
    for (int q = 0; q < 5; q++) {
        const float* src = (q == 0) ? h : (q == 1) ? f1 : (q == 2) ? f2 : (q == 3) ? b1 : b2;
        const float* rp = src + (size_t)arow * HH + quad * 8;
        #pragma unroll
        for (int half = 0; half < 2; half++) {
            float4 v0 = *(const float4*)(rp + half * 32);
            float4 v1 = *(const float4*)(rp + half * 32 + 4);
            float fv[8] = {v0.x, v0.y, v0.z, v0.w, v1.x, v1.y, v1.z, v1.w};
            int4 ahi, alo;
            hilo8(fv, &ahi, &alo);
            int ks = q * 2 + half;
            #pragma unroll
            for (int ct = 0; ct < 4; ct++) {
                int4 bf = fwpk[(ks * 4 + ct) * 64 + ln];
                zacc[ct] = mfma16(ahi, bf, zacc[ct]);
                zacc[ct] = mfma16(alo, bf, zacc[ct]);
            }
        }
    }

    // z -> wave-private bf16 LDS in C-layout (row = quad*4+reg, col = ct*16+lx)
    #pragma unroll
    for (int ct = 0; ct < 4; ct++)
        #pragma unroll
        for (int reg = 0; reg < 4; reg++)
            zb[(quad * 4 + reg) * 68 + ct * 16 + lx] = (ushort_t)f2bf_u(zacc[ct][reg]);

    // z A-frags (row = lx, k = ks2*32 + quad*8 + 0..7) — same-wave DS in-order
    int4 ahf[2];
    {
        const ushort_t* z0 = zb + lx * 68 + quad * 8;
        long long a00, a01, a10, a11;
        __builtin_memcpy(&a00, z0, 8);
        __builtin_memcpy(&a01, z0 + 4, 8);
        __builtin_memcpy(&a10, z0 + 32, 8);
        __builtin_memcpy(&a11, z0 + 36, 8);
        ahf[0] = make_int4((int)a00, (int)(a00 >> 32), (int)a01, (int)(a01 >> 32));
        ahf[1] = make_int4((int)a10, (int)(a10 >> 32), (int)a11, (int)(a11 >> 32));
    }

    // decoder: out[16 x 96] per wave = 6 col-tiles, K = 64 = 2 K-steps
    f4v oacc[6];
    #pragma unroll
    for (int ct2 = 0; ct2 < 6; ct2++) {
        float db = decb[ct2 * 16 + lx];
        oacc[ct2] = (f4v){db, db, db, db};
    }
    #pragma unroll
    for (int ks2 = 0; ks2 < 2; ks2++)
        #pragma unroll
        for (int ct2 = 0; ct2 < 6; ct2++) {
            int4 bf = dwpk[(ks2 * 6 + ct2) * 64 + ln];
            oacc[ct2] = mfma16(ahf[ks2], bf, oacc[ct2]);
        }

    // store: C-layout row m = m0+wave*16+quad*4+reg, col = ct2*16+lx -> (hor,f)
    #pragma unroll
    for (int ct2 = 0; ct2 < 6; ct2++) {
        int col = ct2 * 16 + lx;
        int hor = col >> 3, f = col & 7;
        #pragma unroll
        for (int reg = 0; reg < 4; reg++) {
            int m = m0 + wave * 16 + quad * 4 + reg;
            int b = m / NN; int n = m - b * NN;
            out[(((size_t)b * HORZ + hor) * NN + n) * FF + f] = oacc[ct2][reg];
        }
    }
}

extern "C" void kernel_launch(void* const* d_in, const int* in_sizes, int n_in,
                              void* d_out, int out_size, void* d_ws, size_t ws_size,
                              hipStream_t stream) {
    (void)in_sizes; (void)n_in; (void)out_size; (void)ws_size;
    const float* x     = (const float*)d_in[0];
    const int*   ei    = (const int*)d_in[1];
    const float* ew    = (const float*)d_in[2];
    const float* encW  = (const float*)d_in[3];
    const float* encb  = (const float*)d_in[4];
    const float* emb   = (const float*)d_in[5];
    const float* wih   = (const float*)d_in[6];
    const float* whh   = (const float*)d_in[7];
    const float* bih   = (const float*)d_in[8];
    const float* bhh   = (const float*)d_in[9];
    const float* filtW = (const float*)d_in[10];
    const float* filtb = (const float*)d_in[11];
    const float* decW  = (const float*)d_in[12];
    const float* decb  = (const float*)d_in[13];
    float* out = (float*)d_out;

    float* ws = (float*)d_ws;
    float* h    = ws + OFF_H;
    float* f1   = ws + OFF_F1;
    float* f2   = ws + OFF_F2;
    float* b1   = ws + OFF_B1;
    float* b2   = ws + OFF_B2;
    float* bias = ws + OFF_BIAS;
    float* W1   = ws + OFF_W1;
    float* degf = ws + OFF_DEGF;
    float* degb = ws + OFF_DEGB;
    int* cntf = (int*)(ws + OFF_CNTF);
    int* cntb = (int*)(ws + OFF_CNTB);
    int* ptrf = (int*)(ws + OFF_PTRF);
    int* ptrb = (int*)(ws + OFF_PTRB);
    int* epkf = (int*)(ws + OFF_EPKF);
    int* epkb = (int*)(ws + OFF_EPKB);
    int* flag = (int*)(ws + OFF_FLAG);
    int* fwpk = (int*)(ws + OFF_FWPK);
    int* dwpk = (int*)(ws + OFF_DWPK);

    flag_k<<<1, 64, 0, stream>>>(ei, flag);
    zero_k<<<(40000 + 255) / 256, 256, 0, stream>>>(degf, 40000);
    csr_count_k<<<EE / 256, 256, 0, stream>>>(ei, ew, flag, cntf, cntb, degf, degb);
    scan_k<<<2, 256, 0, stream>>>(cntf, cntb, ptrf, ptrb);
    csr_fill_k<<<EE / 256, 256, 0, stream>>>(ei, ew, flag, degf, degb, ptrf, ptrb,
                                             cntf, cntb, epkf, epkb);
    w1_k<<<(FF * GG + 255) / 256, 256, 0, stream>>>(encW, wih, W1);
    pack_k<<<13, 256, 0, stream>>>(filtW, decW, fwpk, dwpk);
    biasA_k<<<(NN + 63) / 64, 256, 0, stream>>>(emb, encb, wih, bih, bhh, bias);
    gru_k<<<MM / 64, 256, 0, stream>>>(x, bias, W1, whh, bhh, h);
    {
        dim3 g((NN / 2) * BB, 1, 2);
        prop_k<<<g, 128, 0, stream>>>(h,  f1, ptrf, (const long long*)epkf,
                                      h,  b1, ptrb, (const long long*)epkb);
        prop_k<<<g, 128, 0, stream>>>(f1, f2, ptrf, (const long long*)epkf,
                                      b1, b2, ptrb, (const long long*)epkb);
    }
    filtdec_k<<<MM / 64, 256, 0, stream>>>(h, f1, f2, b1, b2,
                                           (const int4*)fwpk, filtb,
                                           (const int4*)dwpk, decb, out);
}

// Round 15
// 475.807 us; speedup vs baseline: 1.0075x; 1.0075x over previous
//
#include <hip/hip_runtime.h>

typedef unsigned short ushort_t;

#define NN 10000
#define BB 8
#define TT 12
#define FF 8
#define HH 64
#define GG 192   // 3H
#define HORZ 12
#define EE 320000
#define MM (BB*NN) // 80000

// exp2-folding constants (r17): R/Z pre-activations scaled by -log2e,
// N pre-activations scaled by 2*log2e, folded into weights/biases.
#define NL2E (-1.4426950408889634f)
#define P2L2E (2.8853900817779268f)

// ---- ws layout (float words) ----
#define OFF_H    0u
#define OFF_F1   5120000u
#define OFF_F2   10240000u
#define OFF_B1   15360000u
#define OFF_B2   20480000u
#define OFF_BIAS 25600000u
#define OFF_W1   27520000u
#define OFF_DEGF 27521536u
#define OFF_DEGB 27531536u
#define OFF_CNTF 27541536u
#define OFF_CNTB 27551536u
#define OFF_PTRF 27561536u
#define OFF_PTRB 27571537u
#define OFF_EPKF 27581538u   // packed (idx, w) int2 per edge, fwd (640000 words)
#define OFF_EPKB 28221538u   // packed (idx, w) int2 per edge, bwd (640000 words)
#define OFF_FLAG 28861538u
// r18: bf16 B-frag packs for MFMA filtdec (appended; +53KB of 115MB ws)
#define OFF_FWPK 28861540u   // filtW frags: 40 sets * 64 lanes * int4 = 10240 words
#define OFF_DWPK 28871780u   // decW frags: 12 sets * 64 lanes * int4 = 3072 words

typedef __attribute__((ext_vector_type(8))) short short8;
typedef __attribute__((ext_vector_type(4))) float f4v;

union I4S8 { int4 i; short8 s; };

__device__ __forceinline__ f4v mfma16(int4 a, int4 b, f4v c) {
    I4S8 ua, ub; ua.i = a; ub.i = b;
    return __builtin_amdgcn_mfma_f32_16x16x32_bf16(ua.s, ub.s, c, 0, 0, 0);
}

__device__ __forceinline__ unsigned f2bf_u(float f) {
    union { float f; unsigned u; } v; v.f = f;
    unsigned x = v.u;
    x += 0x7FFFu + ((x >> 16) & 1u);
    return x >> 16;
}
// pack 8 fp32 -> bf16 (round-to-nearest) fragment
__device__ __forceinline__ int4 hi8(const float* f) {
    unsigned hb[8];
    #pragma unroll
    for (int i = 0; i < 8; i++) hb[i] = f2bf_u(f[i]);
    return make_int4((int)(hb[0]|(hb[1]<<16)), (int)(hb[2]|(hb[3]<<16)),
                     (int)(hb[4]|(hb[5]<<16)), (int)(hb[6]|(hb[7]<<16)));
}
// hi/lo split pack: ahi = bf16(x), alo = bf16(x - float(ahi)) — near-fp32 A operand
__device__ __forceinline__ void hilo8(const float* f, int4* ahi, int4* alo) {
    unsigned hb[8];
    float fl[8];
    #pragma unroll
    for (int i = 0; i < 8; i++) {
        hb[i] = f2bf_u(f[i]);
        union { unsigned u; float f; } hf; hf.u = hb[i] << 16;
        fl[i] = f[i] - hf.f;
    }
    *ahi = make_int4((int)(hb[0]|(hb[1]<<16)), (int)(hb[2]|(hb[3]<<16)),
                     (int)(hb[4]|(hb[5]<<16)), (int)(hb[6]|(hb[7]<<16)));
    *alo = hi8(fl);
}

__device__ __forceinline__ float f4c(const float4& v, int kk) {
    switch (kk) { case 0: return v.x; case 1: return v.y; case 2: return v.z; default: return v.w; }
}
#define FMA4(ACC, W, S) \
    ACC[0] = fmaf(S, W.x, ACC[0]); \
    ACC[1] = fmaf(S, W.y, ACC[1]); \
    ACC[2] = fmaf(S, W.z, ACC[2]); \
    ACC[3] = fmaf(S, W.w, ACC[3]);

// ---------------- utility ----------------
// r21: flag folded into zero_k (block 0 lane 0) — saves one dispatch.
__global__ void init_k(const int* __restrict__ ei, int* flag, float* p, int n) {
    int i = blockIdx.x * 256 + threadIdx.x;
    if (i < n) p[i] = 0.f;
    if (i == 0) {
        int o = ei[1] | ei[3] | ei[5] | ei[7] | ei[9] | ei[11] | ei[13];
        flag[0] = (o == 0) ? 1 : 0;
    }
}

__device__ __forceinline__ void load_edge(const int* __restrict__ ei, int isI64,
                                          int e, int& s, int& t) {
    if (isI64) {
        const long long* p = (const long long*)ei;
        s = (int)p[e]; t = (int)p[EE + e];
    } else {
        s = ei[e]; t = ei[EE + e];
    }
}

// ---------------- CSR build ----------------
__global__ void csr_count_k(const int* __restrict__ ei, const float* __restrict__ ew,
                            const int* __restrict__ flag,
                            int* cnt_f, int* cnt_b, float* deg_f, float* deg_b) {
    int e = blockIdx.x * 256 + threadIdx.x;
    if (e >= EE) return;
    int isI64 = flag[0];
    int s, t; load_edge(ei, isI64, e, s, t);
    if ((unsigned)s >= NN || (unsigned)t >= NN) return;
    float w = ew[e];
    atomicAdd(&cnt_f[t], 1); atomicAdd(&deg_f[t], w);
    atomicAdd(&cnt_b[s], 1); atomicAdd(&deg_b[s], w);
}

__global__ void scan_k(int* cnt_f, int* cnt_b, int* ptr_f, int* ptr_b) {
    int* cnt = blockIdx.x ? cnt_b : cnt_f;
    int* ptr = blockIdx.x ? ptr_b : ptr_f;
    __shared__ int part[256];
    int tid = threadIdx.x;
    const int CH = (NN + 255) / 256;
    int lo = tid * CH, hi = lo + CH; if (hi > NN) hi = NN; if (lo > NN) lo = NN;
    int s = 0;
    for (int i = lo; i < hi; i++) s += cnt[i];
    part[tid] = s;
    __syncthreads();
    if (tid == 0) {
        int run = 0;
        for (int i = 0; i < 256; i++) { int v = part[i]; part[i] = run; run += v; }
        ptr[NN] = run;
    }
    __syncthreads();
    int run = part[tid];
    for (int i = lo; i < hi; i++) { ptr[i] = run; run += cnt[i]; cnt[i] = 0; }
}

__global__ void csr_fill_k(const int* __restrict__ ei, const float* __restrict__ ew,
                           const int* __restrict__ flag,
                           const float* __restrict__ deg_f, const float* __restrict__ deg_b,
                           const int* __restrict__ ptr_f, const int* __restrict__ ptr_b,
                           int* cnt_f, int* cnt_b,
                           int* epk_f, int* epk_b) {
    int e = blockIdx.x * 256 + threadIdx.x;
    if (e >= EE) return;
    int isI64 = flag[0];
    int s, t; load_edge(ei, isI64, e, s, t);
    if ((unsigned)s >= NN || (unsigned)t >= NN) return;
    float w = ew[e];
    float df = deg_f[t];
    float nwf = w / ((df == 0.f) ? 1.f : df);
    int p = ptr_f[t] + atomicAdd(&cnt_f[t], 1);
    epk_f[2 * p] = s; epk_f[2 * p + 1] = __float_as_int(nwf);
    float db = deg_b[s];
    float nwb = w / ((db == 0.f) ? 1.f : db);
    int p2 = ptr_b[s] + atomicAdd(&cnt_b[s], 1);
    epk_b[2 * p2] = t; epk_b[2 * p2 + 1] = __float_as_int(nwb);
}

// ---------------- r21: fused W1 precompute + filt/dec weight packing ----------
// blocks 0..5: W1 = enc_W @ Wih^T (r17 exp2-folded); blocks 6..18: r18 packs.
__global__ void w1pack_k(const float* __restrict__ encW, const float* __restrict__ wih,
                         float* __restrict__ W1,
                         const float* __restrict__ filtW, const float* __restrict__ decW,
                         int* __restrict__ fwpk, int* __restrict__ dwpk) {
    if (blockIdx.x < 6) {
        int id = blockIdx.x * 256 + threadIdx.x;
        if (id >= FF * GG) return;
        int f = id / GG, g = id - f * GG;
        float acc = 0.f;
        for (int hh = 0; hh < HH; hh++)
            acc = fmaf(encW[f * HH + hh], wih[g * HH + hh], acc);
        W1[id] = acc * ((g < 128) ? NL2E : P2L2E);
        return;
    }
    int id = (blockIdx.x - 6) * 256 + threadIdx.x;
    int ln = id & 63, set = id >> 6;
    int quad = ln >> 4, lx = ln & 15;
    if (set < 40) {
        int ks = set >> 2, ct = set & 3;
        float fv[8];
        #pragma unroll
        for (int j = 0; j < 8; j++)
            fv[j] = filtW[(ks * 32 + quad * 8 + j) * 64 + ct * 16 + lx];
        *(int4*)&fwpk[(set * 64 + ln) * 4] = hi8(fv);
    } else if (set < 52) {
        int s2 = set - 40;
        int ks2 = s2 / 6, ct2 = s2 - ks2 * 6;
        float fv[8];
        #pragma unroll
        for (int j = 0; j < 8; j++)
            fv[j] = decW[(ks2 * 32 + quad * 8 + j) * 96 + ct2 * 16 + lx];
        *(int4*)&dwpk[(s2 * 64 + ln) * 4] = hi8(fv);
    }
}

// ---- biasA[n][g] = bih[g] + (g<128? bhh[g]:0) + sum_h (enc_b+emb[n])*Wih[g][h] ----
__global__ __launch_bounds__(256, 2)
void biasA_k(const float* __restrict__ emb, const float* __restrict__ encb,
             const float* __restrict__ wih, const float* __restrict__ bih,
             const float* __restrict__ bhh, float* __restrict__ biasA) {
    __shared__ float wl[HH * GG];   // wl[h][g] = Wih[g][h]
    __shared__ float et[64 * 68];   // enc_b + emb tile
    const int tid = threadIdx.x;
    const int n0 = blockIdx.x * 64;
    for (int idx = tid * 4; idx < GG * HH; idx += 1024) {
        float4 v = *(const float4*)&wih[idx];
        int g = idx >> 6, hh = idx & 63;
        wl[hh * GG + g] = v.x;
        wl[(hh + 1) * GG + g] = v.y;
        wl[(hh + 2) * GG + g] = v.z;
        wl[(hh + 3) * GG + g] = v.w;
    }
    {
        int row = tid >> 2, cc = (tid & 3) * 16;
        int n = n0 + row;
        #pragma unroll
        for (int u = 0; u < 4; u++) {
            float4 e4 = (n < NN) ? *(const float4*)&emb[(size_t)n * HH + cc + u * 4]
                                 : make_float4(0.f, 0.f, 0.f, 0.f);
            float4 b4 = *(const float4*)&encb[cc + u * 4];
            *(float4*)&et[row * 68 + cc + u * 4] =
                make_float4(e4.x + b4.x, e4.y + b4.y, e4.z + b4.z, e4.w + b4.w);
        }
    }
    __syncthreads();
    const int r0 = (tid >> 4) * 4;
    #pragma unroll 1
    for (int p = 0; p < 3; p++) {
        const int c0 = p * 64 + (tid & 15) * 4;
        float acc[4][4];
        float4 bi = *(const float4*)&bih[c0];
        float4 bh = (c0 < 128) ? *(const float4*)&bhh[c0] : make_float4(0.f, 0.f, 0.f, 0.f);
        #pragma unroll
        for (int i = 0; i < 4; i++) {
            acc[i][0] = bi.x + bh.x; acc[i][1] = bi.y + bh.y;
            acc[i][2] = bi.z + bh.z; acc[i][3] = bi.w + bh.w;
        }
        #pragma unroll 4
        for (int k4 = 0; k4 < 64; k4 += 4) {
            float4 hv[4];
            #pragma unroll
            for (int i = 0; i < 4; i++)
                hv[i] = *(const float4*)&et[(r0 + i) * 68 + k4];
            #pragma unroll
            for (int kk = 0; kk < 4; kk++) {
                const float4 wv = *(const float4*)&wl[(k4 + kk) * GG + c0];
                #pragma unroll
                for (int i = 0; i < 4; i++) {
                    float a_ = f4c(hv[i], kk);
                    FMA4(acc[i], wv, a_);
                }
            }
        }
        #pragma unroll
        for (int i = 0; i < 4; i++) {
            int n = n0 + r0 + i;
            if (n < NN)
                *(float4*)&biasA[(size_t)n * GG + c0] =
                    make_float4(acc[i][0], acc[i][1], acc[i][2], acc[i][3]);
        }
    }
}

// ---------------- MFMA GRU: all 12 steps, no barriers in loop ----------------
// h scratch bf16 in A-fragment layout; reads via __builtin_memcpy (alias-safe —
// ushort stores + typed 64b loads were reordered by TBAA in the r7 NaN bug).
// r8 WIN kept: gates div-free. r8 FAILED: launch_bounds(256,4) -> spills.
// r16 NEUTRAL kept: w1f in LDS. r17 WIN: exp2-folding.
// r19 FAILED reverted: per-j MFMA+gate fusion serialized the dep graph
//   (the 4 separated j-streams were buying ILP). This is the r17 structure:
//   gru floor ~78us for this session.
__global__ __launch_bounds__(256, 2)
void gru_k(const float* __restrict__ x, const float* __restrict__ biasA,
           const float* __restrict__ W1, const float* __restrict__ whh,
           const float* __restrict__ bhh, float* __restrict__ h_out) {
    __shared__ int lds_B[24 * 64 * 4];                     // Whh B-frags (24 KB)
    __shared__ int lds_W1[12 * 64 * 4];                    // W1 B-frags (12 KB)
    __shared__ __align__(16) ushort_t lds_hb[4][16 * 68];  // per-wave h bf16

    const int tid = threadIdx.x;
    const int wave = tid >> 6, ln = tid & 63;
    const int quad = ln >> 4, lx = ln & 15;
    const int m0 = blockIdx.x * 64;
    ushort_t* hbw = (ushort_t*)lds_hb[wave];

    // stage Whh B-frags: fid=(c*2+q): B[k = q*32 + (ln>>4)*8 + j][g = c*16 + (ln&15)]
    // r17: columns c<8 (R,Z) scaled by -log2e; c>=8 (N) by 2*log2e.
    #pragma unroll
    for (int it = 0; it < 6; it++) {
        int slot = tid + it * 256;
        int fid = slot >> 6, l2 = slot & 63;
        int c = fid >> 1, q = fid & 1;
        int g = c * 16 + (l2 & 15);
        int k0 = q * 32 + ((l2 >> 4) & 3) * 8;
        float sc = (c < 8) ? NL2E : P2L2E;
        const float* wp = whh + (size_t)g * HH + k0;
        float4 v0 = *(const float4*)wp;
        float4 v1 = *(const float4*)(wp + 4);
        float fv[8] = {v0.x * sc, v0.y * sc, v0.z * sc, v0.w * sc,
                       v1.x * sc, v1.y * sc, v1.z * sc, v1.w * sc};
        *(int4*)&lds_B[slot * 4] = hi8(fv);
    }

    // stage W1 B-frags to LDS (block-uniform; already exp2-scaled by w1pack_k;
    // K=32 padded, only k<8 real -> lanes 0-15 carry data)
    #pragma unroll
    for (int it = 0; it < 3; it++) {
        int slot = tid + it * 256;
        int f = slot >> 6, l2 = slot & 63;
        int4 v = make_int4(0, 0, 0, 0);
        if (l2 < 16) {
            int col = f * 16 + l2;
            float fv[8];
            #pragma unroll
            for (int k = 0; k < 8; k++) fv[k] = W1[k * GG + col];
            v = hi8(fv);
        }
        *(int4*)&lds_W1[slot * 4] = v;
    }

    // per-lane biases (C-layout positions), exp2-scaled at load
    f4v bR[4], bZ[4], bNx[4];
    float bHn[4];
    int rown[4];
    #pragma unroll
    for (int reg = 0; reg < 4; reg++) {
        int m = m0 + wave * 16 + quad * 4 + reg;
        int b = m / NN; rown[reg] = m - b * NN;
    }
    #pragma unroll
    for (int j = 0; j < 4; j++) {
        int c = j * 16 + lx;
        #pragma unroll
        for (int reg = 0; reg < 4; reg++) {
            const float* bp = biasA + (size_t)rown[reg] * GG;
            bR[j][reg]  = bp[c] * NL2E;
            bZ[j][reg]  = bp[64 + c] * NL2E;
            bNx[j][reg] = bp[128 + c] * P2L2E;
        }
        bHn[j] = bhh[128 + c] * P2L2E;
    }

    // x pointer + first-step preload (rows owned: m0 + wave*16 + ln, lanes 0-15)
    const float* xp = x;
    float4 xc0 = make_float4(0.f,0.f,0.f,0.f), xc1 = xc0;
    if (ln < 16) {
        int m = m0 + wave * 16 + ln;
        int b = m / NN; int n = m - b * NN;
        xp = x + ((size_t)(b * TT) * NN + n) * FF;
        xc0 = *(const float4*)xp;
        xc1 = *(const float4*)(xp + 4);
    }

    __syncthreads();   // lds_B + lds_W1 ready (only barrier)

    f4v hp[4];
    #pragma unroll
    for (int j = 0; j < 4; j++) hp[j] = (f4v){0.f, 0.f, 0.f, 0.f};

    #pragma unroll 1
    for (int t = 0; t < TT; t++) {
        // pack current x A-frag (hi only)
        int4 axh = make_int4(0, 0, 0, 0);
        {
            float fv[8] = {xc0.x, xc0.y, xc0.z, xc0.w, xc1.x, xc1.y, xc1.z, xc1.w};
            if (ln < 16) axh = hi8(fv);
        }
        // prefetch next-step x (in flight during MFMAs + gates)
        if (t < TT - 1 && ln < 16) {
            const float* xq = xp + (size_t)(t + 1) * (NN * FF);
            xc0 = *(const float4*)xq;
            xc1 = *(const float4*)(xq + 4);
        }

        // h A-frags from bf16 LDS (A-layout: row=lx, chans q*32+quad*8..+7)
        int4 ahf[2];
        if (t) {
            const ushort_t* h0 = hbw + lx * 68 + quad * 8;
            long long a00, a01, a10, a11;
            __builtin_memcpy(&a00, h0, 8);
            __builtin_memcpy(&a01, h0 + 4, 8);
            __builtin_memcpy(&a10, h0 + 32, 8);
            __builtin_memcpy(&a11, h0 + 36, 8);
            ahf[0] = make_int4((int)a00, (int)(a00 >> 32), (int)a01, (int)(a01 >> 32));
            ahf[1] = make_int4((int)a10, (int)(a10 >> 32), (int)a11, (int)(a11 >> 32));
        }

        f4v accR[4], accZ[4], accNx[4], accNh[4];
        #pragma unroll
        for (int j = 0; j < 4; j++) {
            int4 wR = *(const int4*)&lds_W1[((j    ) * 64 + ln) * 4];
            int4 wZ = *(const int4*)&lds_W1[((j + 4) * 64 + ln) * 4];
            int4 wN = *(const int4*)&lds_W1[((j + 8) * 64 + ln) * 4];
            accR[j]  = mfma16(axh, wR, bR[j]);
            accZ[j]  = mfma16(axh, wZ, bZ[j]);
            accNx[j] = mfma16(axh, wN, bNx[j]);
            accNh[j] = (f4v){bHn[j], bHn[j], bHn[j], bHn[j]};
        }
        if (t) {
            #pragma unroll
            for (int j = 0; j < 4; j++) {
                #pragma unroll
                for (int q = 0; q < 2; q++) {
                    int4 bRf = *(const int4*)&lds_B[((j * 2 + q) * 64 + ln) * 4];
                    int4 bZf = *(const int4*)&lds_B[(((j + 4) * 2 + q) * 64 + ln) * 4];
                    int4 bNf = *(const int4*)&lds_B[(((j + 8) * 2 + q) * 64 + ln) * 4];
                    accR[j]  = mfma16(ahf[q], bRf, accR[j]);
                    accZ[j]  = mfma16(ahf[q], bZf, accZ[j]);
                    accNh[j] = mfma16(ahf[q], bNf, accNh[j]);
                }
            }
        }

        // gates (exp2-folded): rr = rcp(1+exp2(accR')), nn = 1-2*rcp(exp2(pre')+1)
        #pragma unroll
        for (int j = 0; j < 4; j++) {
            #pragma unroll
            for (int reg = 0; reg < 4; reg++) {
                float rr = __builtin_amdgcn_rcpf(1.f + __builtin_amdgcn_exp2f(accR[j][reg]));
                float zz = __builtin_amdgcn_rcpf(1.f + __builtin_amdgcn_exp2f(accZ[j][reg]));
                float pre = fmaf(rr, accNh[j][reg], accNx[j][reg]);
                float e2 = __builtin_amdgcn_exp2f(pre);
                float nn = fmaf(-2.f, __builtin_amdgcn_rcpf(e2 + 1.f), 1.f);
                float hv = fmaf(zz, hp[j][reg] - nn, nn);
                hp[j][reg] = hv;
                hbw[(quad * 4 + reg) * 68 + j * 16 + lx] = (ushort_t)f2bf_u(hv);
            }
        }
    }

    // epilogue: h_out[m][64] straight from registers (C-layout, 64B segments)
    #pragma unroll
    for (int j = 0; j < 4; j++) {
        #pragma unroll
        for (int reg = 0; reg < 4; reg++) {
            int m = m0 + wave * 16 + quad * 4 + reg;
            h_out[(size_t)m * HH + j * 16 + lx] = hp[j][reg];
        }
    }
}

// ---------------- diffusion: uniform-node scalar-addressed gather ----------------
// r9 FAILED: 8 batches/wave killed L2 locality. r10 WIN: scalar addressing.
// r11 FAILED: tid>>6 not provably uniform. r12 WIN: readfirstlane + 1-slice.
// r13 WIN (small): unroll 16. r14 WIN: XCD-pinned batch.
// r20 FAILED reverted: MLP 16->32 neutral-to-negative (past MLP~16 the
//   L2-miss path binds, not in-flight count). This is the r14/r18 body:
//   prop floor ~72-77us for this structure.
__global__ __launch_bounds__(128)
void prop_k(const float* __restrict__ srcF, float* __restrict__ dstF,
            const int* __restrict__ ptrF, const long long* __restrict__ epkF,
            const float* __restrict__ srcB, float* __restrict__ dstB,
            const int* __restrict__ ptrB, const long long* __restrict__ epkB) {
    const int wv = __builtin_amdgcn_readfirstlane(threadIdx.x >> 6);  // SGPR
    const int ln = threadIdx.x & 63;
    const int b = blockIdx.x & 7;                // XCD-pinned batch
    const int node = (blockIdx.x >> 3) * 2 + wv; // provably wave-uniform
    const float* src; float* dst; const int* ptr; const long long* ep;
    if (blockIdx.z == 0) { src = srcF; dst = dstF; ptr = ptrF; ep = epkF; }
    else                 { src = srcB; dst = dstB; ptr = ptrB; ep = epkB; }
    const int uoff = b * (NN * HH) + ln;         // loop-invariant lane offset
    const int e0 = ptr[node], e1 = ptr[node + 1];

    float a0 = 0.f, a1 = 0.f, a2 = 0.f, a3 = 0.f;
    float a4 = 0.f, a5 = 0.f, a6 = 0.f, a7 = 0.f;
    int j = e0;
    for (; j + 16 <= e1; j += 16) {
        long long r0 = ep[j + 0],  r1 = ep[j + 1],  r2 = ep[j + 2],  r3 = ep[j + 3];
        long long r4 = ep[j + 4],  r5 = ep[j + 5],  r6 = ep[j + 6],  r7 = ep[j + 7];
        long long r8 = ep[j + 8],  r9 = ep[j + 9],  rA = ep[j + 10], rB = ep[j + 11];
        long long rC = ep[j + 12], rD = ep[j + 13], rE = ep[j + 14], rF = ep[j + 15];
        float v0 = (src + ((size_t)(int)r0 << 6))[uoff];
        float v1 = (src + ((size_t)(int)r1 << 6))[uoff];
        float v2 = (src + ((size_t)(int)r2 << 6))[uoff];
        float v3 = (src + ((size_t)(int)r3 << 6))[uoff];
        float v4 = (src + ((size_t)(int)r4 << 6))[uoff];
        float v5 = (src + ((size_t)(int)r5 << 6))[uoff];
        float v6 = (src + ((size_t)(int)r6 << 6))[uoff];
        float v7 = (src + ((size_t)(int)r7 << 6))[uoff];
        float v8 = (src + ((size_t)(int)r8 << 6))[uoff];
        float v9 = (src + ((size_t)(int)r9 << 6))[uoff];
        float vA = (src + ((size_t)(int)rA << 6))[uoff];
        float vB = (src + ((size_t)(int)rB << 6))[uoff];
        float vC = (src + ((size_t)(int)rC << 6))[uoff];
        float vD = (src + ((size_t)(int)rD << 6))[uoff];
        float vE = (src + ((size_t)(int)rE << 6))[uoff];
        float vF = (src + ((size_t)(int)rF << 6))[uoff];
        a0 = fmaf(v0, __int_as_float((int)(r0 >> 32)), a0);
        a1 = fmaf(v1, __int_as_float((int)(r1 >> 32)), a1);
        a2 = fmaf(v2, __int_as_float((int)(r2 >> 32)), a2);
        a3 = fmaf(v3, __int_as_float((int)(r3 >> 32)), a3);
        a4 = fmaf(v4, __int_as_float((int)(r4 >> 32)), a4);
        a5 = fmaf(v5, __int_as_float((int)(r5 >> 32)), a5);
        a6 = fmaf(v6, __int_as_float((int)(r6 >> 32)), a6);
        a7 = fmaf(v7, __int_as_float((int)(r7 >> 32)), a7);
        a0 = fmaf(v8, __int_as_float((int)(r8 >> 32)), a0);
        a1 = fmaf(v9, __int_as_float((int)(r9 >> 32)), a1);
        a2 = fmaf(vA, __int_as_float((int)(rA >> 32)), a2);
        a3 = fmaf(vB, __int_as_float((int)(rB >> 32)), a3);
        a4 = fmaf(vC, __int_as_float((int)(rC >> 32)), a4);
        a5 = fmaf(vD, __int_as_float((int)(rD >> 32)), a5);
        a6 = fmaf(vE, __int_as_float((int)(rE >> 32)), a6);
        a7 = fmaf(vF, __int_as_float((int)(rF >> 32)), a7);
    }
    for (; j + 8 <= e1; j += 8) {
        long long r0 = ep[j + 0], r1 = ep[j + 1], r2 = ep[j + 2], r3 = ep[j + 3];
        long long r4 = ep[j + 4], r5 = ep[j + 5], r6 = ep[j + 6], r7 = ep[j + 7];
        float v0 = (src + ((size_t)(int)r0 << 6))[uoff];
        float v1 = (src + ((size_t)(int)r1 << 6))[uoff];
        float v2 = (src + ((size_t)(int)r2 << 6))[uoff];
        float v3 = (src + ((size_t)(int)r3 << 6))[uoff];
        float v4 = (src + ((size_t)(int)r4 << 6))[uoff];
        float v5 = (src + ((size_t)(int)r5 << 6))[uoff];
        float v6 = (src + ((size_t)(int)r6 << 6))[uoff];
        float v7 = (src + ((size_t)(int)r7 << 6))[uoff];
        a0 = fmaf(v0, __int_as_float((int)(r0 >> 32)), a0);
        a1 = fmaf(v1, __int_as_float((int)(r1 >> 32)), a1);
        a2 = fmaf(v2, __int_as_float((int)(r2 >> 32)), a2);
        a3 = fmaf(v3, __int_as_float((int)(r3 >> 32)), a3);
        a4 = fmaf(v4, __int_as_float((int)(r4 >> 32)), a4);
        a5 = fmaf(v5, __int_as_float((int)(r5 >> 32)), a5);
        a6 = fmaf(v6, __int_as_float((int)(r6 >> 32)), a6);
        a7 = fmaf(v7, __int_as_float((int)(r7 >> 32)), a7);
    }
    for (; j < e1; j++) {
        long long r0 = ep[j];
        a0 = fmaf((src + ((size_t)(int)r0 << 6))[uoff],
                  __int_as_float((int)(r0 >> 32)), a0);
    }
    float s = ((a0 + a1) + (a2 + a3)) + ((a4 + a5) + (a6 + a7));
    __builtin_nontemporal_store(s, &dst[((size_t)b * NN + node) * HH + ln]);
}

// ---------------- r18: MFMA filter (K=320) + decoder (K=64) ----------------
// r18 WIN: matrix-core rewrite (prepacked bf16 B-frags, hi/lo-split A, zero
// barriers, LDS 8.7KB): filtdec out of top-5, absmax unchanged.
__global__ __launch_bounds__(256)
void filtdec_k(const float* __restrict__ h, const float* __restrict__ f1,
               const float* __restrict__ f2, const float* __restrict__ b1,
               const float* __restrict__ b2,
               const int4* __restrict__ fwpk, const float* __restrict__ filtb,
               const int4* __restrict__ dwpk, const float* __restrict__ decb,
               float* __restrict__ out) {
    __shared__ __align__(16) ushort_t lds_z[4][16 * 68];
    const int tid = threadIdx.x;
    const int wave = tid >> 6, ln = tid & 63;
    const int quad = ln >> 4, lx = ln & 15;
    const int m0 = blockIdx.x * 64;
    const int arow = m0 + wave * 16 + lx;        // A-frag row for this lane
    ushort_t* zb = (ushort_t*)lds_z[wave];

    // filter accumulators, bias-initialized (C-layout: col = ct*16+lx)
    f4v zacc[4];
    #pragma unroll
    for (int ct = 0; ct < 4; ct++) {
        float fb = filtb[ct * 16 + lx];
        zacc[ct] = (f4v){fb, fb, fb, fb};
    }

    // K = 320 = 5 matrices x 64; per matrix 2 K-steps of 32
    #pragma unroll 1
    for (int q = 0; q < 5; q++) {
        const float* src = (q == 0) ? h : (q == 1) ? f1 : (q == 2) ? f2 : (q == 3) ? b1 : b2;
        const float* rp = src + (size_t)arow * HH + quad * 8;
        #pragma unroll
        for (int half = 0; half < 2; half++) {
            float4 v0 = *(const float4*)(rp + half * 32);
            float4 v1 = *(const float4*)(rp + half * 32 + 4);
            float fv[8] = {v0.x, v0.y, v0.z, v0.w, v1.x, v1.y, v1.z, v1.w};
            int4 ahi, alo;
            hilo8(fv, &ahi, &alo);
            int ks = q * 2 + half;
            #pragma unroll
            for (int ct = 0; ct < 4; ct++) {
                int4 bf = fwpk[(ks * 4 + ct) * 64 + ln];
                zacc[ct] = mfma16(ahi, bf, zacc[ct]);
                zacc[ct] = mfma16(alo, bf, zacc[ct]);
            }
        }
    }

    // z -> wave-private bf16 LDS in C-layout (row = quad*4+reg, col = ct*16+lx)
    #pragma unroll
    for (int ct = 0; ct < 4; ct++)
        #pragma unroll
        for (int reg = 0; reg < 4; reg++)
            zb[(quad * 4 + reg) * 68 + ct * 16 + lx] = (ushort_t)f2bf_u(zacc[ct][reg]);

    // z A-frags (row = lx, k = ks2*32 + quad*8 + 0..7) — same-wave DS in-order
    int4 ahf[2];
    {
        const ushort_t* z0 = zb + lx * 68 + quad * 8;
        long long a00, a01, a10, a11;
        __builtin_memcpy(&a00, z0, 8);
        __builtin_memcpy(&a01, z0 + 4, 8);
        __builtin_memcpy(&a10, z0 + 32, 8);
        __builtin_memcpy(&a11, z0 + 36, 8);
        ahf[0] = make_int4((int)a00, (int)(a00 >> 32), (int)a01, (int)(a01 >> 32));
        ahf[1] = make_int4((int)a10, (int)(a10 >> 32), (int)a11, (int)(a11 >> 32));
    }

    // decoder: out[16 x 96] per wave = 6 col-tiles, K = 64 = 2 K-steps
    f4v oacc[6];
    #pragma unroll
    for (int ct2 = 0; ct2 < 6; ct2++) {
        float db = decb[ct2 * 16 + lx];
        oacc[ct2] = (f4v){db, db, db, db};
    }
    #pragma unroll
    for (int ks2 = 0; ks2 < 2; ks2++)
        #pragma unroll
        for (int ct2 = 0; ct2 < 6; ct2++) {
            int4 bf = dwpk[(ks2 * 6 + ct2) * 64 + ln];
            oacc[ct2] = mfma16(ahf[ks2], bf, oacc[ct2]);
        }

    // store: C-layout row m = m0+wave*16+quad*4+reg, col = ct2*16+lx -> (hor,f)
    #pragma unroll
    for (int ct2 = 0; ct2 < 6; ct2++) {
        int col = ct2 * 16 + lx;
        int hor = col >> 3, f = col & 7;
        #pragma unroll
        for (int reg = 0; reg < 4; reg++) {
            int m = m0 + wave * 16 + quad * 4 + reg;
            int b = m / NN; int n = m - b * NN;
            out[(((size_t)b * HORZ + hor) * NN + n) * FF + f] = oacc[ct2][reg];
        }
    }
}

extern "C" void kernel_launch(void* const* d_in, const int* in_sizes, int n_in,
                              void* d_out, int out_size, void* d_ws, size_t ws_size,
                              hipStream_t stream) {
    (void)in_sizes; (void)n_in; (void)out_size; (void)ws_size;
    const float* x     = (const float*)d_in[0];
    const int*   ei    = (const int*)d_in[1];
    const float* ew    = (const float*)d_in[2];
    const float* encW  = (const float*)d_in[3];
    const float* encb  = (const float*)d_in[4];
    const float* emb   = (const float*)d_in[5];
    const float* wih   = (const float*)d_in[6];
    const float* whh   = (const float*)d_in[7];
    const float* bih   = (const float*)d_in[8];
    const float* bhh   = (const float*)d_in[9];
    const float* filtW = (const float*)d_in[10];
    const float* filtb = (const float*)d_in[11];
    const float* decW  = (const float*)d_in[12];
    const float* decb  = (const float*)d_in[13];
    float* out = (float*)d_out;

    float* ws = (float*)d_ws;
    float* h    = ws + OFF_H;
    float* f1   = ws + OFF_F1;
    float* f2   = ws + OFF_F2;
    float* b1   = ws + OFF_B1;
    float* b2   = ws + OFF_B2;
    float* bias = ws + OFF_BIAS;
    float* W1   = ws + OFF_W1;
    float* degf = ws + OFF_DEGF;
    float* degb = ws + OFF_DEGB;
    int* cntf = (int*)(ws + OFF_CNTF);
    int* cntb = (int*)(ws + OFF_CNTB);
    int* ptrf = (int*)(ws + OFF_PTRF);
    int* ptrb = (int*)(ws + OFF_PTRB);
    int* epkf = (int*)(ws + OFF_EPKF);
    int* epkb = (int*)(ws + OFF_EPKB);
    int* flag = (int*)(ws + OFF_FLAG);
    int* fwpk = (int*)(ws + OFF_FWPK);
    int* dwpk = (int*)(ws + OFF_DWPK);

    init_k<<<(40000 + 255) / 256, 256, 0, stream>>>(ei, flag, degf, 40000);
    csr_count_k<<<EE / 256, 256, 0, stream>>>(ei, ew, flag, cntf, cntb, degf, degb);
    scan_k<<<2, 256, 0, stream>>>(cntf, cntb, ptrf, ptrb);
    csr_fill_k<<<EE / 256, 256, 0, stream>>>(ei, ew, flag, degf, degb, ptrf, ptrb,
                                             cntf, cntb, epkf, epkb);
    w1pack_k<<<19, 256, 0, stream>>>(encW, wih, W1, filtW, decW, fwpk, dwpk);
    biasA_k<<<(NN + 63) / 64, 256, 0, stream>>>(emb, encb, wih, bih, bhh, bias);
    gru_k<<<MM / 64, 256, 0, stream>>>(x, bias, W1, whh, bhh, h);
    {
        dim3 g((NN / 2) * BB, 1, 2);
        prop_k<<<g, 128, 0, stream>>>(h,  f1, ptrf, (const long long*)epkf,
                                      h,  b1, ptrb, (const long long*)epkb);
        prop_k<<<g, 128, 0, stream>>>(f1, f2, ptrf, (const long long*)epkf,
                                      b1, b2, ptrb, (const long long*)epkb);
    }
    filtdec_k<<<MM / 64, 256, 0, stream>>>(h, f1, f2, b1, b2,
                                           (const int4*)fwpk, filtb,
                                           (const int4*)dwpk, decb, out);
}